// Round 3
// baseline (262.453 us; speedup 1.0000x reference)
//
#include <hip/hip_runtime.h>

// AttnBlock on MI355X — round 3: pv restructured (BN=256, 512thr, z=4,
// halved E re-read), exp2-native softmax, attnT aliased onto hT.

typedef __bf16 bf16;
typedef __attribute__((ext_vector_type(8))) __bf16 bf16x8;
typedef __attribute__((ext_vector_type(4))) __bf16 bf16x4;
typedef __attribute__((ext_vector_type(4))) float f32x4;

#define CC 512
#define NN 4096
#define BM 128
#define BN 128
#define BK 64
// 512^-0.5 * log2(e): folded into qT so se_gemm uses exp2f directly
#define SCALE_L2E 0.06376237870903338f

__device__ __forceinline__ void gload16(const bf16* g, bf16* l) {
    __builtin_amdgcn_global_load_lds(
        (const __attribute__((address_space(1))) unsigned int*)g,
        (__attribute__((address_space(3))) unsigned int*)l, 16, 0, 0);
}

// ---------------------------------------------------------------------------
// 128x128 MFMA GEMM core (4 waves). A: row-major [M,K]. B: [N,K] row-major.
// global_load_lds width=16, linear LDS, st-16x32 XOR swizzle on source+read.
// ---------------------------------------------------------------------------
__device__ __forceinline__ void gemm_core(
    const bf16* __restrict__ A, int lda,
    const bf16* __restrict__ B, int ldb,
    int kBeg, int kEnd, int m0, int n0, f32x4 acc[4][4])
{
    __shared__ __align__(16) bf16 Als[BM][BK];
    __shared__ __align__(16) bf16 Bls[BN][BK];
    const int t    = threadIdx.x;
    const int lane = t & 63;
    const int wid  = t >> 6;
    const int wm   = (wid >> 1) * 64;
    const int wn   = (wid & 1) * 64;
    const int fr   = lane & 15;
    const int kq   = lane >> 4;
    const int r_   = t >> 3;
    const int cbs  = (t & 7) ^ (r_ & 7);
    const int dcol = (t & 7) * 8;
    const int cs0  = ((kq)     ^ (fr & 7)) * 8;
    const int cs1  = ((kq + 4) ^ (fr & 7)) * 8;

    for (int k0 = kBeg; k0 < kEnd; k0 += BK) {
        const bf16* Ag = A + (size_t)(m0 + r_) * lda + (k0 + cbs * 8);
        const bf16* Bg = B + (size_t)(n0 + r_) * ldb + (k0 + cbs * 8);
        #pragma unroll
        for (int i = 0; i < 4; ++i)
            gload16(Ag + (size_t)(i * 32) * lda, &Als[i * 32 + r_][dcol]);
        #pragma unroll
        for (int i = 0; i < 4; ++i)
            gload16(Bg + (size_t)(i * 32) * ldb, &Bls[i * 32 + r_][dcol]);
        __syncthreads();
        #pragma unroll
        for (int h = 0; h < 2; ++h) {
            const int cs = h ? cs1 : cs0;
            bf16x8 af[4], bg[4];
            #pragma unroll
            for (int f = 0; f < 4; ++f) {
                af[f] = *(const bf16x8*)&Als[wm + f * 16 + fr][cs];
                bg[f] = *(const bf16x8*)&Bls[wn + f * 16 + fr][cs];
            }
            #pragma unroll
            for (int fm = 0; fm < 4; ++fm)
                #pragma unroll
                for (int fn = 0; fn < 4; ++fn)
                    acc[fm][fn] = __builtin_amdgcn_mfma_f32_16x16x32_bf16(
                        af[fm], bg[fn], acc[fm][fn], 0, 0, 0);
        }
        __syncthreads();
    }
}

// ---------------------------------------------------------------------------
// Prep kernels
// ---------------------------------------------------------------------------
__global__ __launch_bounds__(256) void convert_w_kernel(
    const float* __restrict__ qw, const float* __restrict__ kw,
    const float* __restrict__ vw, const float* __restrict__ pw,
    bf16* __restrict__ dst)
{
    const int which = blockIdx.y;
    const float* src = which == 0 ? qw : which == 1 ? kw : which == 2 ? vw : pw;
    bf16* d = dst + (size_t)which * (CC * CC);
    const int f4 = blockIdx.x * 256 + threadIdx.x;
    float4 v = ((const float4*)src)[f4];
    bf16x4 o;
    o[0] = (bf16)v.x; o[1] = (bf16)v.y; o[2] = (bf16)v.z; o[3] = (bf16)v.w;
    ((bf16x4*)d)[f4] = o;
}

__global__ __launch_bounds__(256) void gn_stats_kernel(
    const float* __restrict__ x, float* __restrict__ mr)
{
    const int bg = blockIdx.x;
    const float4* base = (const float4*)(x + (size_t)bg * 16 * NN);
    const int t = threadIdx.x;
    float s = 0.f, sq = 0.f;
    #pragma unroll 4
    for (int i = 0; i < 64; ++i) {
        float4 v = base[i * 256 + t];
        s  += v.x + v.y + v.z + v.w;
        sq += v.x * v.x + v.y * v.y + v.z * v.z + v.w * v.w;
    }
    #pragma unroll
    for (int o = 32; o > 0; o >>= 1) { s += __shfl_xor(s, o); sq += __shfl_xor(sq, o); }
    __shared__ float rs[4], rq[4];
    const int lane = t & 63, wid = t >> 6;
    if (lane == 0) { rs[wid] = s; rq[wid] = sq; }
    __syncthreads();
    if (t == 0) {
        float S = rs[0] + rs[1] + rs[2] + rs[3];
        float Q = rq[0] + rq[1] + rq[2] + rq[3];
        const float invn = 1.f / 65536.f;
        float mean = S * invn;
        float var  = Q * invn - mean * mean;
        mr[bg * 2]     = mean;
        mr[bg * 2 + 1] = rsqrtf(var + 1e-6f);
    }
}

// GN apply + transpose: x[b,c,n] fp32 -> hT[b,n,c] bf16
__global__ __launch_bounds__(256) void gn_apply_T_kernel(
    const float* __restrict__ x, const float* __restrict__ gw,
    const float* __restrict__ gb, const float* __restrict__ mr,
    bf16* __restrict__ hT)
{
    const int b  = blockIdx.z;
    const int n0 = blockIdx.x * 64;
    const int c0 = blockIdx.y * 64;
    const int t  = threadIdx.x;
    const int tn = t & 15, tc = t >> 4;
    float o[4][4];
    #pragma unroll
    for (int j = 0; j < 4; ++j) {
        const int c = c0 + tc * 4 + j;
        const int bg = b * 32 + (c >> 4);
        const float mean = mr[bg * 2], rstd = mr[bg * 2 + 1];
        const float w  = gw[c] * rstd;
        const float bb = gb[c] - mean * w;
        float4 v = *(const float4*)(x + ((size_t)(b * CC + c)) * NN + n0 + tn * 4);
        o[j][0] = v.x * w + bb; o[j][1] = v.y * w + bb;
        o[j][2] = v.z * w + bb; o[j][3] = v.w * w + bb;
    }
    bf16* dst = hT + (size_t)b * (size_t)NN * CC;
    #pragma unroll
    for (int i = 0; i < 4; ++i) {
        bf16x4 w4;
        w4[0] = (bf16)o[0][i]; w4[1] = (bf16)o[1][i];
        w4[2] = (bf16)o[2][i]; w4[3] = (bf16)o[3][i];
        *(bf16x4*)(dst + (size_t)(n0 + tn * 4 + i) * CC + c0 + tc * 4) = w4;
    }
}

// ---------------------------------------------------------------------------
// GEMM kernels
// ---------------------------------------------------------------------------
// qT/kT[b][n][o] = sum_c hT[b][n][c] * w[o][c] (+bias); q scaled by SCALE_L2E
__global__ __launch_bounds__(256) void qk_gemm_kernel(
    const bf16* __restrict__ hT, const bf16* __restrict__ wbf,
    const float* __restrict__ qb, const float* __restrict__ kb,
    bf16* __restrict__ qT, bf16* __restrict__ kT)
{
    const int z = blockIdx.z, b = z >> 1, w = z & 1;
    const size_t CN = (size_t)CC * NN;
    const bf16* A = hT + (size_t)b * CN;
    const bf16* B = wbf + (size_t)w * CC * CC;
    const float* bias = w ? kb : qb;
    bf16* outp = (w ? kT : qT) + (size_t)b * CN;
    const int m0 = blockIdx.y * BM, n0 = blockIdx.x * BN;
    f32x4 acc[4][4] = {};
    gemm_core(A, CC, B, CC, 0, CC, m0, n0, acc);
    const int lane = threadIdx.x & 63, wid = threadIdx.x >> 6;
    const int wm = (wid >> 1) * 64, wn = (wid & 1) * 64;
    const int cf = lane & 15, rb = (lane >> 4) * 4;
    #pragma unroll
    for (int fm = 0; fm < 4; ++fm)
      #pragma unroll
      for (int fn = 0; fn < 4; ++fn)
        #pragma unroll
        for (int r = 0; r < 4; ++r) {
            int row = m0 + wm + fm * 16 + rb + r;
            int col = n0 + wn + fn * 16 + cf;
            float val = acc[fm][fn][r] + bias[col];
            if (w == 0) val *= SCALE_L2E;
            outp[(size_t)row * CC + col] = (bf16)val;
        }
}

// v[b][c][n] = sum_k vw[c][k] * hT[b][n][k] + vb[c]
__global__ __launch_bounds__(256) void v_gemm_kernel(
    const bf16* __restrict__ vw, const bf16* __restrict__ hT,
    const float* __restrict__ vb, bf16* __restrict__ vout)
{
    const int b = blockIdx.z;
    const size_t CN = (size_t)CC * NN;
    const bf16* B = hT + (size_t)b * CN;
    bf16* outp = vout + (size_t)b * CN;
    const int m0 = blockIdx.y * BM, n0 = blockIdx.x * BN;
    f32x4 acc[4][4] = {};
    gemm_core(vw, CC, B, CC, 0, CC, m0, n0, acc);
    const int lane = threadIdx.x & 63, wid = threadIdx.x >> 6;
    const int wm = (wid >> 1) * 64, wn = (wid & 1) * 64;
    const int cf = lane & 15, rb = (lane >> 4) * 4;
    #pragma unroll
    for (int fm = 0; fm < 4; ++fm)
      #pragma unroll
      for (int fn = 0; fn < 4; ++fn)
        #pragma unroll
        for (int r = 0; r < 4; ++r) {
            int row = m0 + wm + fm * 16 + rb + r;    // c
            int col = n0 + wn + fn * 16 + cf;        // n
            outp[(size_t)row * NN + col] = (bf16)(acc[fm][fn][r] + vb[row]);
        }
}

// E[i][j] = exp2(qT_b[i,:].kT_b[j,:]); rowsum[i] += partials (atomic)
__global__ __launch_bounds__(256) void se_gemm_kernel(
    const bf16* __restrict__ qT_b, const bf16* __restrict__ kT_b,
    bf16* __restrict__ E, float* __restrict__ rowsum)
{
    const int m0 = blockIdx.y * BM, n0 = blockIdx.x * BN;
    f32x4 acc[4][4] = {};
    gemm_core(qT_b, CC, kT_b, CC, 0, CC, m0, n0, acc);
    const int lane = threadIdx.x & 63, wid = threadIdx.x >> 6;
    const int wm = (wid >> 1) * 64, wn = (wid & 1) * 64;
    const int cf = lane & 15, rb = (lane >> 4) * 4;
    #pragma unroll
    for (int fm = 0; fm < 4; ++fm)
      #pragma unroll
      for (int fn = 0; fn < 4; ++fn)
        #pragma unroll
        for (int r = 0; r < 4; ++r) {
            float e = exp2f(fminf(acc[fm][fn][r], 86.f));
            acc[fm][fn][r] = e;
            E[(size_t)(m0 + wm + fm * 16 + rb + r) * NN
              + (n0 + wn + fn * 16 + cf)] = (bf16)e;
        }
    #pragma unroll
    for (int fm = 0; fm < 4; ++fm)
      #pragma unroll
      for (int r = 0; r < 4; ++r) {
          float s = acc[fm][0][r] + acc[fm][1][r] + acc[fm][2][r] + acc[fm][3][r];
          s += __shfl_xor(s, 1); s += __shfl_xor(s, 2);
          s += __shfl_xor(s, 4); s += __shfl_xor(s, 8);
          if (cf == 0)
              atomicAdd(&rowsum[m0 + wm + fm * 16 + rb + r], s);
      }
}

// attnTf[i][c] += sum_{j in slice} E[i][j] * v[c][j]
// 512 threads = 8 waves (2m x 4n), BM=128, BN=256, K-slice 1024 (z=4).
__global__ __launch_bounds__(512) void pv_gemm_kernel(
    const bf16* __restrict__ E, const bf16* __restrict__ v_b,
    float* __restrict__ attnTf)
{
    __shared__ __align__(16) bf16 Als[128][64];   // E tile  [i][j]
    __shared__ __align__(16) bf16 Bls[256][64];   // v tile  [c][j]
    const int t    = threadIdx.x;
    const int lane = t & 63;
    const int wid  = t >> 6;             // 0..7
    const int wm   = (wid >> 2) * 64;    // 0,64
    const int wn   = (wid & 3) * 64;     // 0..192
    const int fr   = lane & 15;
    const int kq   = lane >> 4;
    const int m0   = blockIdx.y * 128;
    const int n0   = blockIdx.x * 256;
    const int kB   = blockIdx.z * 1024;
    const int r_   = t >> 3;             // 0..63
    const int cbs  = (t & 7) ^ (r_ & 7);
    const int dcol = (t & 7) * 8;
    const int cs0  = ((kq)     ^ (fr & 7)) * 8;
    const int cs1  = ((kq + 4) ^ (fr & 7)) * 8;

    f32x4 acc[4][4] = {};
    for (int k0 = kB; k0 < kB + 1024; k0 += BK) {
        const bf16* Ag = E   + (size_t)(m0 + r_) * NN + (k0 + cbs * 8);
        const bf16* Bg = v_b + (size_t)(n0 + r_) * NN + (k0 + cbs * 8);
        gload16(Ag,                      &Als[r_][dcol]);
        gload16(Ag + (size_t)64 * NN,    &Als[64 + r_][dcol]);
        #pragma unroll
        for (int i = 0; i < 4; ++i)
            gload16(Bg + (size_t)(i * 64) * NN, &Bls[i * 64 + r_][dcol]);
        __syncthreads();
        #pragma unroll
        for (int h = 0; h < 2; ++h) {
            const int cs = h ? cs1 : cs0;
            bf16x8 af[4], bg[4];
            #pragma unroll
            for (int f = 0; f < 4; ++f) {
                af[f] = *(const bf16x8*)&Als[wm + f * 16 + fr][cs];
                bg[f] = *(const bf16x8*)&Bls[wn + f * 16 + fr][cs];
            }
            #pragma unroll
            for (int fm = 0; fm < 4; ++fm)
                #pragma unroll
                for (int fn = 0; fn < 4; ++fn)
                    acc[fm][fn] = __builtin_amdgcn_mfma_f32_16x16x32_bf16(
                        af[fm], bg[fn], acc[fm][fn], 0, 0, 0);
        }
        __syncthreads();
    }
    const int cf = lane & 15, rb = (lane >> 4) * 4;
    #pragma unroll
    for (int fm = 0; fm < 4; ++fm)
      #pragma unroll
      for (int fn = 0; fn < 4; ++fn)
        #pragma unroll
        for (int r = 0; r < 4; ++r)
            atomicAdd(&attnTf[(size_t)(m0 + wm + fm * 16 + rb + r) * CC
                              + (n0 + wn + fn * 16 + cf)], acc[fm][fn][r]);
}

// attnT_b[i][c] = attnTf[i][c] / rowsum[i]
__global__ __launch_bounds__(256) void norm_kernel(
    const float* __restrict__ attnTf, const float* __restrict__ rowsum,
    bf16* __restrict__ attnT_b)
{
    const int idx = blockIdx.x * 256 + threadIdx.x;
    const int i = idx >> 7;
    const float inv = 1.f / rowsum[i];
    float4 u = ((const float4*)attnTf)[idx];
    bf16x4 o;
    o[0] = (bf16)(u.x * inv); o[1] = (bf16)(u.y * inv);
    o[2] = (bf16)(u.z * inv); o[3] = (bf16)(u.w * inv);
    ((bf16x4*)attnT_b)[idx] = o;
}

// out[b][o][n] = sum_c attnT[b][n][c] * pw[o][c] + pb[o] + x[b][o][n]
__global__ __launch_bounds__(256) void proj_gemm_kernel(
    const bf16* __restrict__ attnT, const bf16* __restrict__ pwb,
    const float* __restrict__ pb, const float* __restrict__ x,
    float* __restrict__ outp)
{
    const int b = blockIdx.z;
    const size_t CN = (size_t)CC * NN;
    const bf16* A = attnT + (size_t)b * CN;
    const int m0 = blockIdx.y * BM, n0 = blockIdx.x * BN;
    f32x4 acc[4][4] = {};
    gemm_core(A, CC, pwb, CC, 0, CC, m0, n0, acc);
    const int lane = threadIdx.x & 63, wid = threadIdx.x >> 6;
    const int wm = (wid >> 1) * 64, wn = (wid & 1) * 64;
    const int cf = lane & 15, rb = (lane >> 4) * 4;
    #pragma unroll
    for (int fm = 0; fm < 4; ++fm)
      #pragma unroll
      for (int fn = 0; fn < 4; ++fn) {
          int rowg = m0 + wm + fm * 16 + rb;          // n (contiguous)
          int colg = n0 + wn + fn * 16 + cf;          // o
          size_t base = (size_t)b * CN + (size_t)colg * NN + rowg;
          float4 rx = *(const float4*)(x + base);
          float pbv = pb[colg];
          float4 o;
          o.x = acc[fm][fn][0] + pbv + rx.x;
          o.y = acc[fm][fn][1] + pbv + rx.y;
          o.z = acc[fm][fn][2] + pbv + rx.z;
          o.w = acc[fm][fn][3] + pbv + rx.w;
          *(float4*)(outp + base) = o;
      }
}

// ---------------------------------------------------------------------------
extern "C" void kernel_launch(void* const* d_in, const int* in_sizes, int n_in,
                              void* d_out, int out_size, void* d_ws, size_t ws_size,
                              hipStream_t stream)
{
    const float* x   = (const float*)d_in[0];
    const float* gnw = (const float*)d_in[1];
    const float* gnb = (const float*)d_in[2];
    const float* qw  = (const float*)d_in[3];
    const float* qb  = (const float*)d_in[4];
    const float* kw  = (const float*)d_in[5];
    const float* kb  = (const float*)d_in[6];
    const float* vw  = (const float*)d_in[7];
    const float* vb  = (const float*)d_in[8];
    const float* pw  = (const float*)d_in[9];
    const float* pb  = (const float*)d_in[10];
    float* outp = (float*)d_out;

    char* ws = (char*)d_ws;
    size_t off = 0;
    auto alloc = [&](size_t bytes) -> char* {
        char* p = ws + off;
        off = (off + bytes + 255) & ~(size_t)255;
        return p;
    };
    const size_t CN = (size_t)CC * NN;
    bf16*  wbf    = (bf16*)alloc(4 * (size_t)CC * CC * sizeof(bf16)); // 2MB
    bf16*  hT     = (bf16*)alloc(2 * CN * sizeof(bf16));              // 8MB (aliased as attnT after v_gemm)
    bf16*  qT     = (bf16*)alloc(2 * CN * sizeof(bf16));              // 8MB
    bf16*  kT     = (bf16*)alloc(2 * CN * sizeof(bf16));              // 8MB
    bf16*  vbuf   = (bf16*)alloc(2 * CN * sizeof(bf16));              // 8MB
    bf16*  E      = (bf16*)alloc((size_t)NN * NN * sizeof(bf16));     // 32MB
    float* attnTf = (float*)alloc(CN * sizeof(float) + NN * sizeof(float)); // 8MB+16KB
    float* rowsum = attnTf + CN;
    float* mr     = (float*)alloc(64 * 2 * sizeof(float));
    bf16*  attnT  = hT;  // hT is dead after v_gemm; reuse for attnT

    convert_w_kernel<<<dim3(256, 4), 256, 0, stream>>>(qw, kw, vw, pw, wbf);
    gn_stats_kernel<<<64, 256, 0, stream>>>(x, mr);
    gn_apply_T_kernel<<<dim3(NN / 64, CC / 64, 2), 256, 0, stream>>>(
        x, gnw, gnb, mr, hT);

    qk_gemm_kernel<<<dim3(CC / BN, NN / BM, 4), 256, 0, stream>>>(
        hT, wbf, qb, kb, qT, kT);
    v_gemm_kernel<<<dim3(NN / BN, CC / BM, 2), 256, 0, stream>>>(
        wbf + 2 * (size_t)CC * CC, hT, vb, vbuf);

    for (int b = 0; b < 2; ++b) {
        hipMemsetAsync(attnTf, 0, CN * sizeof(float) + NN * sizeof(float), stream);
        se_gemm_kernel<<<dim3(NN / BN, NN / BM), 256, 0, stream>>>(
            qT + (size_t)b * CN, kT + (size_t)b * CN, E, rowsum);
        pv_gemm_kernel<<<dim3(2, 32, 4), 512, 0, stream>>>(
            E, vbuf + (size_t)b * CN, attnTf);
        norm_kernel<<<CN / 1024, 256, 0, stream>>>(
            attnTf, rowsum, attnT + (size_t)b * CN);
    }

    proj_gemm_kernel<<<dim3(CC / BN, NN / BM, 2), 256, 0, stream>>>(
        attnT, wbf + 3 * (size_t)CC * CC, pb, x, outp);
}

// Round 4
// 254.219 us; speedup vs baseline: 1.0324x; 1.0324x over previous
//
#include <hip/hip_runtime.h>

// AttnBlock on MI355X — round 4: 2-phase double-buffered staging (T3-min)
// in all GEMM cores; otherwise identical to round 3.

typedef __bf16 bf16;
typedef __attribute__((ext_vector_type(8))) __bf16 bf16x8;
typedef __attribute__((ext_vector_type(4))) __bf16 bf16x4;
typedef __attribute__((ext_vector_type(4))) float f32x4;

#define CC 512
#define NN 4096
#define BM 128
#define BN 128
#define BK 64
// 512^-0.5 * log2(e): folded into qT so se_gemm uses exp2f directly
#define SCALE_L2E 0.06376237870903338f

__device__ __forceinline__ void gload16(const bf16* g, bf16* l) {
    __builtin_amdgcn_global_load_lds(
        (const __attribute__((address_space(1))) unsigned int*)g,
        (__attribute__((address_space(3))) unsigned int*)l, 16, 0, 0);
}

// ---------------------------------------------------------------------------
// 128x128 MFMA GEMM core (4 waves), 2-phase double-buffered.
// A: row-major [M,K]. B: [N,K] row-major. global_load_lds width=16,
// linear LDS dest, st-16x32 XOR swizzle on source + read.
// ---------------------------------------------------------------------------
__device__ __forceinline__ void gemm_core(
    const bf16* __restrict__ A, int lda,
    const bf16* __restrict__ B, int ldb,
    int kBeg, int kEnd, int m0, int n0, f32x4 acc[4][4])
{
    __shared__ __align__(16) bf16 Als[2][BM][BK];
    __shared__ __align__(16) bf16 Bls[2][BN][BK];
    const int t    = threadIdx.x;
    const int lane = t & 63;
    const int wid  = t >> 6;
    const int wm   = (wid >> 1) * 64;
    const int wn   = (wid & 1) * 64;
    const int fr   = lane & 15;
    const int kq   = lane >> 4;
    const int r_   = t >> 3;
    const int cbs  = (t & 7) ^ (r_ & 7);
    const int dcol = (t & 7) * 8;
    const int cs0  = ((kq)     ^ (fr & 7)) * 8;
    const int cs1  = ((kq + 4) ^ (fr & 7)) * 8;

    const bf16* Ab = A + (size_t)(m0 + r_) * lda + cbs * 8;
    const bf16* Bb = B + (size_t)(n0 + r_) * ldb + cbs * 8;

#define STAGE_G(bufi, kk) do {                                              \
        _Pragma("unroll")                                                   \
        for (int i = 0; i < 4; ++i)                                         \
            gload16(Ab + (kk) + (size_t)(i * 32) * lda,                     \
                    &Als[bufi][i * 32 + r_][dcol]);                         \
        _Pragma("unroll")                                                   \
        for (int i = 0; i < 4; ++i)                                         \
            gload16(Bb + (kk) + (size_t)(i * 32) * ldb,                     \
                    &Bls[bufi][i * 32 + r_][dcol]);                         \
    } while (0)

    int cur = 0;
    STAGE_G(0, kBeg);
    __syncthreads();
    for (int k0 = kBeg; k0 < kEnd; k0 += BK) {
        if (k0 + BK < kEnd) STAGE_G(cur ^ 1, k0 + BK);   // prefetch next tile
        #pragma unroll
        for (int h = 0; h < 2; ++h) {
            const int cs = h ? cs1 : cs0;
            bf16x8 af[4], bg[4];
            #pragma unroll
            for (int f = 0; f < 4; ++f) {
                af[f] = *(const bf16x8*)&Als[cur][wm + f * 16 + fr][cs];
                bg[f] = *(const bf16x8*)&Bls[cur][wn + f * 16 + fr][cs];
            }
            #pragma unroll
            for (int fm = 0; fm < 4; ++fm)
                #pragma unroll
                for (int fn = 0; fn < 4; ++fn)
                    acc[fm][fn] = __builtin_amdgcn_mfma_f32_16x16x32_bf16(
                        af[fm], bg[fn], acc[fm][fn], 0, 0, 0);
        }
        __syncthreads();   // drains prefetch (vmcnt0) after compute hid it
        cur ^= 1;
    }
#undef STAGE_G
}

// ---------------------------------------------------------------------------
// Prep kernels
// ---------------------------------------------------------------------------
__global__ __launch_bounds__(256) void convert_w_kernel(
    const float* __restrict__ qw, const float* __restrict__ kw,
    const float* __restrict__ vw, const float* __restrict__ pw,
    bf16* __restrict__ dst)
{
    const int which = blockIdx.y;
    const float* src = which == 0 ? qw : which == 1 ? kw : which == 2 ? vw : pw;
    bf16* d = dst + (size_t)which * (CC * CC);
    const int f4 = blockIdx.x * 256 + threadIdx.x;
    float4 v = ((const float4*)src)[f4];
    bf16x4 o;
    o[0] = (bf16)v.x; o[1] = (bf16)v.y; o[2] = (bf16)v.z; o[3] = (bf16)v.w;
    ((bf16x4*)d)[f4] = o;
}

__global__ __launch_bounds__(256) void gn_stats_kernel(
    const float* __restrict__ x, float* __restrict__ mr)
{
    const int bg = blockIdx.x;
    const float4* base = (const float4*)(x + (size_t)bg * 16 * NN);
    const int t = threadIdx.x;
    float s = 0.f, sq = 0.f;
    #pragma unroll 4
    for (int i = 0; i < 64; ++i) {
        float4 v = base[i * 256 + t];
        s  += v.x + v.y + v.z + v.w;
        sq += v.x * v.x + v.y * v.y + v.z * v.z + v.w * v.w;
    }
    #pragma unroll
    for (int o = 32; o > 0; o >>= 1) { s += __shfl_xor(s, o); sq += __shfl_xor(sq, o); }
    __shared__ float rs[4], rq[4];
    const int lane = t & 63, wid = t >> 6;
    if (lane == 0) { rs[wid] = s; rq[wid] = sq; }
    __syncthreads();
    if (t == 0) {
        float S = rs[0] + rs[1] + rs[2] + rs[3];
        float Q = rq[0] + rq[1] + rq[2] + rq[3];
        const float invn = 1.f / 65536.f;
        float mean = S * invn;
        float var  = Q * invn - mean * mean;
        mr[bg * 2]     = mean;
        mr[bg * 2 + 1] = rsqrtf(var + 1e-6f);
    }
}

// GN apply + transpose: x[b,c,n] fp32 -> hT[b,n,c] bf16
__global__ __launch_bounds__(256) void gn_apply_T_kernel(
    const float* __restrict__ x, const float* __restrict__ gw,
    const float* __restrict__ gb, const float* __restrict__ mr,
    bf16* __restrict__ hT)
{
    const int b  = blockIdx.z;
    const int n0 = blockIdx.x * 64;
    const int c0 = blockIdx.y * 64;
    const int t  = threadIdx.x;
    const int tn = t & 15, tc = t >> 4;
    float o[4][4];
    #pragma unroll
    for (int j = 0; j < 4; ++j) {
        const int c = c0 + tc * 4 + j;
        const int bg = b * 32 + (c >> 4);
        const float mean = mr[bg * 2], rstd = mr[bg * 2 + 1];
        const float w  = gw[c] * rstd;
        const float bb = gb[c] - mean * w;
        float4 v = *(const float4*)(x + ((size_t)(b * CC + c)) * NN + n0 + tn * 4);
        o[j][0] = v.x * w + bb; o[j][1] = v.y * w + bb;
        o[j][2] = v.z * w + bb; o[j][3] = v.w * w + bb;
    }
    bf16* dst = hT + (size_t)b * (size_t)NN * CC;
    #pragma unroll
    for (int i = 0; i < 4; ++i) {
        bf16x4 w4;
        w4[0] = (bf16)o[0][i]; w4[1] = (bf16)o[1][i];
        w4[2] = (bf16)o[2][i]; w4[3] = (bf16)o[3][i];
        *(bf16x4*)(dst + (size_t)(n0 + tn * 4 + i) * CC + c0 + tc * 4) = w4;
    }
}

// ---------------------------------------------------------------------------
// GEMM kernels
// ---------------------------------------------------------------------------
__global__ __launch_bounds__(256) void qk_gemm_kernel(
    const bf16* __restrict__ hT, const bf16* __restrict__ wbf,
    const float* __restrict__ qb, const float* __restrict__ kb,
    bf16* __restrict__ qT, bf16* __restrict__ kT)
{
    const int z = blockIdx.z, b = z >> 1, w = z & 1;
    const size_t CN = (size_t)CC * NN;
    const bf16* A = hT + (size_t)b * CN;
    const bf16* B = wbf + (size_t)w * CC * CC;
    const float* bias = w ? kb : qb;
    bf16* outp = (w ? kT : qT) + (size_t)b * CN;
    const int m0 = blockIdx.y * BM, n0 = blockIdx.x * BN;
    f32x4 acc[4][4] = {};
    gemm_core(A, CC, B, CC, 0, CC, m0, n0, acc);
    const int lane = threadIdx.x & 63, wid = threadIdx.x >> 6;
    const int wm = (wid >> 1) * 64, wn = (wid & 1) * 64;
    const int cf = lane & 15, rb = (lane >> 4) * 4;
    #pragma unroll
    for (int fm = 0; fm < 4; ++fm)
      #pragma unroll
      for (int fn = 0; fn < 4; ++fn)
        #pragma unroll
        for (int r = 0; r < 4; ++r) {
            int row = m0 + wm + fm * 16 + rb + r;
            int col = n0 + wn + fn * 16 + cf;
            float val = acc[fm][fn][r] + bias[col];
            if (w == 0) val *= SCALE_L2E;
            outp[(size_t)row * CC + col] = (bf16)val;
        }
}

__global__ __launch_bounds__(256) void v_gemm_kernel(
    const bf16* __restrict__ vw, const bf16* __restrict__ hT,
    const float* __restrict__ vb, bf16* __restrict__ vout)
{
    const int b = blockIdx.z;
    const size_t CN = (size_t)CC * NN;
    const bf16* B = hT + (size_t)b * CN;
    bf16* outp = vout + (size_t)b * CN;
    const int m0 = blockIdx.y * BM, n0 = blockIdx.x * BN;
    f32x4 acc[4][4] = {};
    gemm_core(vw, CC, B, CC, 0, CC, m0, n0, acc);
    const int lane = threadIdx.x & 63, wid = threadIdx.x >> 6;
    const int wm = (wid >> 1) * 64, wn = (wid & 1) * 64;
    const int cf = lane & 15, rb = (lane >> 4) * 4;
    #pragma unroll
    for (int fm = 0; fm < 4; ++fm)
      #pragma unroll
      for (int fn = 0; fn < 4; ++fn)
        #pragma unroll
        for (int r = 0; r < 4; ++r) {
            int row = m0 + wm + fm * 16 + rb + r;    // c
            int col = n0 + wn + fn * 16 + cf;        // n
            outp[(size_t)row * NN + col] = (bf16)(acc[fm][fn][r] + vb[row]);
        }
}

// E[i][j] = exp2(qT_b[i,:].kT_b[j,:]); rowsum[i] += partials (atomic)
__global__ __launch_bounds__(256) void se_gemm_kernel(
    const bf16* __restrict__ qT_b, const bf16* __restrict__ kT_b,
    bf16* __restrict__ E, float* __restrict__ rowsum)
{
    const int m0 = blockIdx.y * BM, n0 = blockIdx.x * BN;
    f32x4 acc[4][4] = {};
    gemm_core(qT_b, CC, kT_b, CC, 0, CC, m0, n0, acc);
    const int lane = threadIdx.x & 63, wid = threadIdx.x >> 6;
    const int wm = (wid >> 1) * 64, wn = (wid & 1) * 64;
    const int cf = lane & 15, rb = (lane >> 4) * 4;
    #pragma unroll
    for (int fm = 0; fm < 4; ++fm)
      #pragma unroll
      for (int fn = 0; fn < 4; ++fn)
        #pragma unroll
        for (int r = 0; r < 4; ++r) {
            float e = exp2f(fminf(acc[fm][fn][r], 86.f));
            acc[fm][fn][r] = e;
            E[(size_t)(m0 + wm + fm * 16 + rb + r) * NN
              + (n0 + wn + fn * 16 + cf)] = (bf16)e;
        }
    #pragma unroll
    for (int fm = 0; fm < 4; ++fm)
      #pragma unroll
      for (int r = 0; r < 4; ++r) {
          float s = acc[fm][0][r] + acc[fm][1][r] + acc[fm][2][r] + acc[fm][3][r];
          s += __shfl_xor(s, 1); s += __shfl_xor(s, 2);
          s += __shfl_xor(s, 4); s += __shfl_xor(s, 8);
          if (cf == 0)
              atomicAdd(&rowsum[m0 + wm + fm * 16 + rb + r], s);
      }
}

// attnTf[i][c] += sum_{j in slice} E[i][j] * v[c][j]
// 512 threads = 8 waves (2m x 4n), BM=128, BN=256, K-slice 1024 (z=4),
// double-buffered (96KB LDS).
__global__ __launch_bounds__(512) void pv_gemm_kernel(
    const bf16* __restrict__ E, const bf16* __restrict__ v_b,
    float* __restrict__ attnTf)
{
    __shared__ __align__(16) bf16 Als[2][128][64];   // E tile  [i][j]
    __shared__ __align__(16) bf16 Bls[2][256][64];   // v tile  [c][j]
    const int t    = threadIdx.x;
    const int lane = t & 63;
    const int wid  = t >> 6;             // 0..7
    const int wm   = (wid >> 2) * 64;
    const int wn   = (wid & 3) * 64;
    const int fr   = lane & 15;
    const int kq   = lane >> 4;
    const int m0   = blockIdx.y * 128;
    const int n0   = blockIdx.x * 256;
    const int kB   = blockIdx.z * 1024;
    const int r_   = t >> 3;             // 0..63
    const int cbs  = (t & 7) ^ (r_ & 7);
    const int dcol = (t & 7) * 8;
    const int cs0  = ((kq)     ^ (fr & 7)) * 8;
    const int cs1  = ((kq + 4) ^ (fr & 7)) * 8;

    const bf16* Ab = E   + (size_t)(m0 + r_) * NN + cbs * 8;
    const bf16* Bb = v_b + (size_t)(n0 + r_) * NN + cbs * 8;

#define STAGE_P(bufi, kk) do {                                              \
        gload16(Ab + (kk),                    &Als[bufi][r_][dcol]);        \
        gload16(Ab + (kk) + (size_t)64 * NN,  &Als[bufi][64 + r_][dcol]);   \
        _Pragma("unroll")                                                   \
        for (int i = 0; i < 4; ++i)                                         \
            gload16(Bb + (kk) + (size_t)(i * 64) * NN,                      \
                    &Bls[bufi][i * 64 + r_][dcol]);                         \
    } while (0)

    f32x4 acc[4][4] = {};
    int cur = 0;
    STAGE_P(0, kB);
    __syncthreads();
    for (int k0 = kB; k0 < kB + 1024; k0 += BK) {
        if (k0 + BK < kB + 1024) STAGE_P(cur ^ 1, k0 + BK);
        #pragma unroll
        for (int h = 0; h < 2; ++h) {
            const int cs = h ? cs1 : cs0;
            bf16x8 af[4], bg[4];
            #pragma unroll
            for (int f = 0; f < 4; ++f) {
                af[f] = *(const bf16x8*)&Als[cur][wm + f * 16 + fr][cs];
                bg[f] = *(const bf16x8*)&Bls[cur][wn + f * 16 + fr][cs];
            }
            #pragma unroll
            for (int fm = 0; fm < 4; ++fm)
                #pragma unroll
                for (int fn = 0; fn < 4; ++fn)
                    acc[fm][fn] = __builtin_amdgcn_mfma_f32_16x16x32_bf16(
                        af[fm], bg[fn], acc[fm][fn], 0, 0, 0);
        }
        __syncthreads();
        cur ^= 1;
    }
#undef STAGE_P
    const int cf = lane & 15, rb = (lane >> 4) * 4;
    #pragma unroll
    for (int fm = 0; fm < 4; ++fm)
      #pragma unroll
      for (int fn = 0; fn < 4; ++fn)
        #pragma unroll
        for (int r = 0; r < 4; ++r)
            atomicAdd(&attnTf[(size_t)(m0 + wm + fm * 16 + rb + r) * CC
                              + (n0 + wn + fn * 16 + cf)], acc[fm][fn][r]);
}

// attnT_b[i][c] = attnTf[i][c] / rowsum[i]
__global__ __launch_bounds__(256) void norm_kernel(
    const float* __restrict__ attnTf, const float* __restrict__ rowsum,
    bf16* __restrict__ attnT_b)
{
    const int idx = blockIdx.x * 256 + threadIdx.x;
    const int i = idx >> 7;
    const float inv = 1.f / rowsum[i];
    float4 u = ((const float4*)attnTf)[idx];
    bf16x4 o;
    o[0] = (bf16)(u.x * inv); o[1] = (bf16)(u.y * inv);
    o[2] = (bf16)(u.z * inv); o[3] = (bf16)(u.w * inv);
    ((bf16x4*)attnT_b)[idx] = o;
}

// out[b][o][n] = sum_c attnT[b][n][c] * pw[o][c] + pb[o] + x[b][o][n]
__global__ __launch_bounds__(256) void proj_gemm_kernel(
    const bf16* __restrict__ attnT, const bf16* __restrict__ pwb,
    const float* __restrict__ pb, const float* __restrict__ x,
    float* __restrict__ outp)
{
    const int b = blockIdx.z;
    const size_t CN = (size_t)CC * NN;
    const bf16* A = attnT + (size_t)b * CN;
    const int m0 = blockIdx.y * BM, n0 = blockIdx.x * BN;
    f32x4 acc[4][4] = {};
    gemm_core(A, CC, pwb, CC, 0, CC, m0, n0, acc);
    const int lane = threadIdx.x & 63, wid = threadIdx.x >> 6;
    const int wm = (wid >> 1) * 64, wn = (wid & 1) * 64;
    const int cf = lane & 15, rb = (lane >> 4) * 4;
    #pragma unroll
    for (int fm = 0; fm < 4; ++fm)
      #pragma unroll
      for (int fn = 0; fn < 4; ++fn) {
          int rowg = m0 + wm + fm * 16 + rb;          // n (contiguous)
          int colg = n0 + wn + fn * 16 + cf;          // o
          size_t base = (size_t)b * CN + (size_t)colg * NN + rowg;
          float4 rx = *(const float4*)(x + base);
          float pbv = pb[colg];
          float4 o;
          o.x = acc[fm][fn][0] + pbv + rx.x;
          o.y = acc[fm][fn][1] + pbv + rx.y;
          o.z = acc[fm][fn][2] + pbv + rx.z;
          o.w = acc[fm][fn][3] + pbv + rx.w;
          *(float4*)(outp + base) = o;
      }
}

// ---------------------------------------------------------------------------
extern "C" void kernel_launch(void* const* d_in, const int* in_sizes, int n_in,
                              void* d_out, int out_size, void* d_ws, size_t ws_size,
                              hipStream_t stream)
{
    const float* x   = (const float*)d_in[0];
    const float* gnw = (const float*)d_in[1];
    const float* gnb = (const float*)d_in[2];
    const float* qw  = (const float*)d_in[3];
    const float* qb  = (const float*)d_in[4];
    const float* kw  = (const float*)d_in[5];
    const float* kb  = (const float*)d_in[6];
    const float* vw  = (const float*)d_in[7];
    const float* vb  = (const float*)d_in[8];
    const float* pw  = (const float*)d_in[9];
    const float* pb  = (const float*)d_in[10];
    float* outp = (float*)d_out;

    char* ws = (char*)d_ws;
    size_t off = 0;
    auto alloc = [&](size_t bytes) -> char* {
        char* p = ws + off;
        off = (off + bytes + 255) & ~(size_t)255;
        return p;
    };
    const size_t CN = (size_t)CC * NN;
    bf16*  wbf    = (bf16*)alloc(4 * (size_t)CC * CC * sizeof(bf16)); // 2MB
    bf16*  hT     = (bf16*)alloc(2 * CN * sizeof(bf16));              // 8MB (aliased as attnT later)
    bf16*  qT     = (bf16*)alloc(2 * CN * sizeof(bf16));              // 8MB
    bf16*  kT     = (bf16*)alloc(2 * CN * sizeof(bf16));              // 8MB
    bf16*  vbuf   = (bf16*)alloc(2 * CN * sizeof(bf16));              // 8MB
    bf16*  E      = (bf16*)alloc((size_t)NN * NN * sizeof(bf16));     // 32MB
    float* attnTf = (float*)alloc(CN * sizeof(float) + NN * sizeof(float)); // 8MB+16KB
    float* rowsum = attnTf + CN;
    float* mr     = (float*)alloc(64 * 2 * sizeof(float));
    bf16*  attnT  = hT;  // hT dead after v_gemm; reuse

    convert_w_kernel<<<dim3(256, 4), 256, 0, stream>>>(qw, kw, vw, pw, wbf);
    gn_stats_kernel<<<64, 256, 0, stream>>>(x, mr);
    gn_apply_T_kernel<<<dim3(NN / 64, CC / 64, 2), 256, 0, stream>>>(
        x, gnw, gnb, mr, hT);

    qk_gemm_kernel<<<dim3(CC / BN, NN / BM, 4), 256, 0, stream>>>(
        hT, wbf, qb, kb, qT, kT);
    v_gemm_kernel<<<dim3(NN / BN, CC / BM, 2), 256, 0, stream>>>(
        wbf + 2 * (size_t)CC * CC, hT, vb, vbuf);

    for (int b = 0; b < 2; ++b) {
        hipMemsetAsync(attnTf, 0, CN * sizeof(float) + NN * sizeof(float), stream);
        se_gemm_kernel<<<dim3(NN / BN, NN / BM), 256, 0, stream>>>(
            qT + (size_t)b * CN, kT + (size_t)b * CN, E, rowsum);
        pv_gemm_kernel<<<dim3(2, 32, 4), 512, 0, stream>>>(
            E, vbuf + (size_t)b * CN, attnTf);
        norm_kernel<<<CN / 1024, 256, 0, stream>>>(
            attnTf, rowsum, attnT + (size_t)b * CN);
    }

    proj_gemm_kernel<<<dim3(CC / BN, NN / BM, 2), 256, 0, stream>>>(
        attnT, wbf + 3 * (size_t)CC * CC, pb, x, outp);
}

// Round 5
// 206.729 us; speedup vs baseline: 1.2696x; 1.2297x over previous
//
#include <hip/hip_runtime.h>

// AttnBlock on MI355X — round 5: algebraic fusion. attn/proj reassociated:
//   out = (W~ . E^T)/rowsum + wb + pb + x,  W~ = (pw.vw) . hT^T
// Eliminates v, attn, norm, proj and all fp32-atomic RMW on attn.

typedef __bf16 bf16;
typedef __attribute__((ext_vector_type(8))) __bf16 bf16x8;
typedef __attribute__((ext_vector_type(4))) __bf16 bf16x4;
typedef __attribute__((ext_vector_type(4))) float f32x4;

#define CC 512
#define NN 4096
#define BM 128
#define BN 128
#define BK 64
// 512^-0.5 * log2(e): folded into qT so se_gemm uses exp2f directly
#define SCALE_L2E 0.06376237870903338f

__device__ __forceinline__ void gload16(const bf16* g, bf16* l) {
    __builtin_amdgcn_global_load_lds(
        (const __attribute__((address_space(1))) unsigned int*)g,
        (__attribute__((address_space(3))) unsigned int*)l, 16, 0, 0);
}

// ---------------------------------------------------------------------------
// 128x128 MFMA GEMM core (4 waves), 2-phase double-buffered.
// A: row-major [M,K]. B: [N,K] row-major. global_load_lds width=16,
// linear LDS dest, st-16x32 XOR swizzle on source + read.
// ---------------------------------------------------------------------------
__device__ __forceinline__ void gemm_core(
    const bf16* __restrict__ A, int lda,
    const bf16* __restrict__ B, int ldb,
    int kBeg, int kEnd, int m0, int n0, f32x4 acc[4][4])
{
    __shared__ __align__(16) bf16 Als[2][BM][BK];
    __shared__ __align__(16) bf16 Bls[2][BN][BK];
    const int t    = threadIdx.x;
    const int lane = t & 63;
    const int wid  = t >> 6;
    const int wm   = (wid >> 1) * 64;
    const int wn   = (wid & 1) * 64;
    const int fr   = lane & 15;
    const int kq   = lane >> 4;
    const int r_   = t >> 3;
    const int cbs  = (t & 7) ^ (r_ & 7);
    const int dcol = (t & 7) * 8;
    const int cs0  = ((kq)     ^ (fr & 7)) * 8;
    const int cs1  = ((kq + 4) ^ (fr & 7)) * 8;

    const bf16* Ab = A + (size_t)(m0 + r_) * lda + cbs * 8;
    const bf16* Bb = B + (size_t)(n0 + r_) * ldb + cbs * 8;

#define STAGE_G(bufi, kk) do {                                              \
        _Pragma("unroll")                                                   \
        for (int i = 0; i < 4; ++i)                                         \
            gload16(Ab + (kk) + (size_t)(i * 32) * lda,                     \
                    &Als[bufi][i * 32 + r_][dcol]);                         \
        _Pragma("unroll")                                                   \
        for (int i = 0; i < 4; ++i)                                         \
            gload16(Bb + (kk) + (size_t)(i * 32) * ldb,                     \
                    &Bls[bufi][i * 32 + r_][dcol]);                         \
    } while (0)

    int cur = 0;
    STAGE_G(0, kBeg);
    __syncthreads();
    for (int k0 = kBeg; k0 < kEnd; k0 += BK) {
        if (k0 + BK < kEnd) STAGE_G(cur ^ 1, k0 + BK);
        #pragma unroll
        for (int h = 0; h < 2; ++h) {
            const int cs = h ? cs1 : cs0;
            bf16x8 af[4], bg[4];
            #pragma unroll
            for (int f = 0; f < 4; ++f) {
                af[f] = *(const bf16x8*)&Als[cur][wm + f * 16 + fr][cs];
                bg[f] = *(const bf16x8*)&Bls[cur][wn + f * 16 + fr][cs];
            }
            #pragma unroll
            for (int fm = 0; fm < 4; ++fm)
                #pragma unroll
                for (int fn = 0; fn < 4; ++fn)
                    acc[fm][fn] = __builtin_amdgcn_mfma_f32_16x16x32_bf16(
                        af[fm], bg[fn], acc[fm][fn], 0, 0, 0);
        }
        __syncthreads();
        cur ^= 1;
    }
#undef STAGE_G
}

// ---------------------------------------------------------------------------
// 64x128 MFMA GEMM core (4 waves, 2m x 2n of 32x64), double-buffered, 48KB.
// ---------------------------------------------------------------------------
__device__ __forceinline__ void gemm_core64(
    const bf16* __restrict__ A, int lda,
    const bf16* __restrict__ B, int ldb,
    int kBeg, int kEnd, int m0, int n0, f32x4 acc[2][4])
{
    __shared__ __align__(16) bf16 Als[2][64][BK];
    __shared__ __align__(16) bf16 Bls[2][BN][BK];
    const int t    = threadIdx.x;
    const int lane = t & 63;
    const int wid  = t >> 6;
    const int wm   = (wid >> 1) * 32;
    const int wn   = (wid & 1) * 64;
    const int fr   = lane & 15;
    const int kq   = lane >> 4;
    const int r_   = t >> 3;
    const int cbs  = (t & 7) ^ (r_ & 7);
    const int dcol = (t & 7) * 8;
    const int cs0  = ((kq)     ^ (fr & 7)) * 8;
    const int cs1  = ((kq + 4) ^ (fr & 7)) * 8;

    const bf16* Ab = A + (size_t)(m0 + r_) * lda + cbs * 8;
    const bf16* Bb = B + (size_t)(n0 + r_) * ldb + cbs * 8;

#define STAGE_G64(bufi, kk) do {                                            \
        _Pragma("unroll")                                                   \
        for (int i = 0; i < 2; ++i)                                         \
            gload16(Ab + (kk) + (size_t)(i * 32) * lda,                     \
                    &Als[bufi][i * 32 + r_][dcol]);                         \
        _Pragma("unroll")                                                   \
        for (int i = 0; i < 4; ++i)                                         \
            gload16(Bb + (kk) + (size_t)(i * 32) * ldb,                     \
                    &Bls[bufi][i * 32 + r_][dcol]);                         \
    } while (0)

    int cur = 0;
    STAGE_G64(0, kBeg);
    __syncthreads();
    for (int k0 = kBeg; k0 < kEnd; k0 += BK) {
        if (k0 + BK < kEnd) STAGE_G64(cur ^ 1, k0 + BK);
        #pragma unroll
        for (int h = 0; h < 2; ++h) {
            const int cs = h ? cs1 : cs0;
            bf16x8 af[2], bg[4];
            #pragma unroll
            for (int f = 0; f < 2; ++f)
                af[f] = *(const bf16x8*)&Als[cur][wm + f * 16 + fr][cs];
            #pragma unroll
            for (int f = 0; f < 4; ++f)
                bg[f] = *(const bf16x8*)&Bls[cur][wn + f * 16 + fr][cs];
            #pragma unroll
            for (int fm = 0; fm < 2; ++fm)
                #pragma unroll
                for (int fn = 0; fn < 4; ++fn)
                    acc[fm][fn] = __builtin_amdgcn_mfma_f32_16x16x32_bf16(
                        af[fm], bg[fn], acc[fm][fn], 0, 0, 0);
        }
        __syncthreads();
        cur ^= 1;
    }
#undef STAGE_G64
}

// ---------------------------------------------------------------------------
// Prep kernels
// ---------------------------------------------------------------------------
// which: 0->qw(slot0), 1->kw(slot1), 2->pw(slot3)
__global__ __launch_bounds__(256) void convert_w_kernel(
    const float* __restrict__ qw, const float* __restrict__ kw,
    const float* __restrict__ pw, bf16* __restrict__ dst)
{
    const int which = blockIdx.y;
    const float* src = which == 0 ? qw : which == 1 ? kw : pw;
    const int slot  = which == 2 ? 3 : which;
    bf16* d = dst + (size_t)slot * (CC * CC);
    const int f4 = blockIdx.x * 256 + threadIdx.x;
    float4 v = ((const float4*)src)[f4];
    bf16x4 o;
    o[0] = (bf16)v.x; o[1] = (bf16)v.y; o[2] = (bf16)v.z; o[3] = (bf16)v.w;
    ((bf16x4*)d)[f4] = o;
}

// vwT[k][c] = vw[c][k]  (fp32 -> bf16, 64x64 register-blocklet transpose)
__global__ __launch_bounds__(256) void vwT_kernel(
    const float* __restrict__ vw, bf16* __restrict__ vwT)
{
    const int k0 = blockIdx.x * 64;
    const int c0 = blockIdx.y * 64;
    const int t  = threadIdx.x;
    const int tk = t & 15, tc = t >> 4;
    float o[4][4];
    #pragma unroll
    for (int j = 0; j < 4; ++j) {
        const int c = c0 + tc * 4 + j;
        float4 v = *(const float4*)(vw + (size_t)c * CC + k0 + tk * 4);
        o[j][0] = v.x; o[j][1] = v.y; o[j][2] = v.z; o[j][3] = v.w;
    }
    #pragma unroll
    for (int i = 0; i < 4; ++i) {
        bf16x4 w4;
        w4[0] = (bf16)o[0][i]; w4[1] = (bf16)o[1][i];
        w4[2] = (bf16)o[2][i]; w4[3] = (bf16)o[3][i];
        *(bf16x4*)(vwT + (size_t)(k0 + tk * 4 + i) * CC + c0 + tc * 4) = w4;
    }
}

// wb[o] = sum_c pw[o][c] * vb[c]   (fp32)
__global__ __launch_bounds__(256) void wb_kernel(
    const float* __restrict__ pw, const float* __restrict__ vb,
    float* __restrict__ wb)
{
    const int o = blockIdx.x * 256 + threadIdx.x;
    const float4* row = (const float4*)(pw + (size_t)o * CC);
    const float4* v4  = (const float4*)vb;
    float s = 0.f;
    #pragma unroll 4
    for (int i = 0; i < 128; ++i) {
        float4 a = row[i], b = v4[i];
        s += a.x * b.x + a.y * b.y + a.z * b.z + a.w * b.w;
    }
    wb[o] = s;
}

__global__ __launch_bounds__(256) void gn_stats_kernel(
    const float* __restrict__ x, float* __restrict__ mr)
{
    const int bg = blockIdx.x;
    const float4* base = (const float4*)(x + (size_t)bg * 16 * NN);
    const int t = threadIdx.x;
    float s = 0.f, sq = 0.f;
    #pragma unroll 4
    for (int i = 0; i < 64; ++i) {
        float4 v = base[i * 256 + t];
        s  += v.x + v.y + v.z + v.w;
        sq += v.x * v.x + v.y * v.y + v.z * v.z + v.w * v.w;
    }
    #pragma unroll
    for (int o = 32; o > 0; o >>= 1) { s += __shfl_xor(s, o); sq += __shfl_xor(sq, o); }
    __shared__ float rs[4], rq[4];
    const int lane = t & 63, wid = t >> 6;
    if (lane == 0) { rs[wid] = s; rq[wid] = sq; }
    __syncthreads();
    if (t == 0) {
        float S = rs[0] + rs[1] + rs[2] + rs[3];
        float Q = rq[0] + rq[1] + rq[2] + rq[3];
        const float invn = 1.f / 65536.f;
        float mean = S * invn;
        float var  = Q * invn - mean * mean;
        mr[bg * 2]     = mean;
        mr[bg * 2 + 1] = rsqrtf(var + 1e-6f);
    }
}

// GN apply + transpose: x[b,c,n] fp32 -> hT[b,n,c] bf16
__global__ __launch_bounds__(256) void gn_apply_T_kernel(
    const float* __restrict__ x, const float* __restrict__ gw,
    const float* __restrict__ gb, const float* __restrict__ mr,
    bf16* __restrict__ hT)
{
    const int b  = blockIdx.z;
    const int n0 = blockIdx.x * 64;
    const int c0 = blockIdx.y * 64;
    const int t  = threadIdx.x;
    const int tn = t & 15, tc = t >> 4;
    float o[4][4];
    #pragma unroll
    for (int j = 0; j < 4; ++j) {
        const int c = c0 + tc * 4 + j;
        const int bg = b * 32 + (c >> 4);
        const float mean = mr[bg * 2], rstd = mr[bg * 2 + 1];
        const float w  = gw[c] * rstd;
        const float bb = gb[c] - mean * w;
        float4 v = *(const float4*)(x + ((size_t)(b * CC + c)) * NN + n0 + tn * 4);
        o[j][0] = v.x * w + bb; o[j][1] = v.y * w + bb;
        o[j][2] = v.z * w + bb; o[j][3] = v.w * w + bb;
    }
    bf16* dst = hT + (size_t)b * (size_t)NN * CC;
    #pragma unroll
    for (int i = 0; i < 4; ++i) {
        bf16x4 w4;
        w4[0] = (bf16)o[0][i]; w4[1] = (bf16)o[1][i];
        w4[2] = (bf16)o[2][i]; w4[3] = (bf16)o[3][i];
        *(bf16x4*)(dst + (size_t)(n0 + tn * 4 + i) * CC + c0 + tc * 4) = w4;
    }
}

// ---------------------------------------------------------------------------
// GEMM kernels
// ---------------------------------------------------------------------------
__global__ __launch_bounds__(256) void qk_gemm_kernel(
    const bf16* __restrict__ hT, const bf16* __restrict__ wbf,
    const float* __restrict__ qb, const float* __restrict__ kb,
    bf16* __restrict__ qT, bf16* __restrict__ kT)
{
    const int z = blockIdx.z, b = z >> 1, w = z & 1;
    const size_t CN = (size_t)CC * NN;
    const bf16* A = hT + (size_t)b * CN;
    const bf16* B = wbf + (size_t)w * CC * CC;
    const float* bias = w ? kb : qb;
    bf16* outp = (w ? kT : qT) + (size_t)b * CN;
    const int m0 = blockIdx.y * BM, n0 = blockIdx.x * BN;
    f32x4 acc[4][4] = {};
    gemm_core(A, CC, B, CC, 0, CC, m0, n0, acc);
    const int lane = threadIdx.x & 63, wid = threadIdx.x >> 6;
    const int wm = (wid >> 1) * 64, wn = (wid & 1) * 64;
    const int cf = lane & 15, rb = (lane >> 4) * 4;
    #pragma unroll
    for (int fm = 0; fm < 4; ++fm)
      #pragma unroll
      for (int fn = 0; fn < 4; ++fn)
        #pragma unroll
        for (int r = 0; r < 4; ++r) {
            int row = m0 + wm + fm * 16 + rb + r;
            int col = n0 + wn + fn * 16 + cf;
            float val = acc[fm][fn][r] + bias[col];
            if (w == 0) val *= SCALE_L2E;
            outp[(size_t)row * CC + col] = (bf16)val;
        }
}

// fw[o][k] = sum_c pw[o][c] * vwT[k][c]    (M=512,N=512,K=512)
__global__ __launch_bounds__(256) void fw_gemm_kernel(
    const bf16* __restrict__ pwb, const bf16* __restrict__ vwT,
    bf16* __restrict__ fw)
{
    const int m0 = blockIdx.y * BM, n0 = blockIdx.x * BN;
    f32x4 acc[4][4] = {};
    gemm_core(pwb, CC, vwT, CC, 0, CC, m0, n0, acc);
    const int lane = threadIdx.x & 63, wid = threadIdx.x >> 6;
    const int wm = (wid >> 1) * 64, wn = (wid & 1) * 64;
    const int cf = lane & 15, rb = (lane >> 4) * 4;
    #pragma unroll
    for (int fm = 0; fm < 4; ++fm)
      #pragma unroll
      for (int fn = 0; fn < 4; ++fn)
        #pragma unroll
        for (int r = 0; r < 4; ++r)
            fw[(size_t)(m0 + wm + fm * 16 + rb + r) * CC
               + (n0 + wn + fn * 16 + cf)] = (bf16)acc[fm][fn][r];
}

// W~[b][o][j] = sum_k fw[o][k] * hT[b][j][k]   (M=512,N=4096,K=512)
__global__ __launch_bounds__(256) void w_gemm_kernel(
    const bf16* __restrict__ fw, const bf16* __restrict__ hT,
    bf16* __restrict__ Wt)
{
    const int b = blockIdx.z;
    const size_t CN = (size_t)CC * NN;
    const int m0 = blockIdx.y * 64, n0 = blockIdx.x * BN;
    f32x4 acc[2][4] = {};
    gemm_core64(fw, CC, hT + (size_t)b * CN, CC, 0, CC, m0, n0, acc);
    bf16* outp = Wt + (size_t)b * CN;
    const int lane = threadIdx.x & 63, wid = threadIdx.x >> 6;
    const int wm = (wid >> 1) * 32, wn = (wid & 1) * 64;
    const int cf = lane & 15, rb = (lane >> 4) * 4;
    #pragma unroll
    for (int fm = 0; fm < 2; ++fm)
      #pragma unroll
      for (int fn = 0; fn < 4; ++fn)
        #pragma unroll
        for (int r = 0; r < 4; ++r)
            outp[(size_t)(m0 + wm + fm * 16 + rb + r) * NN
                 + (n0 + wn + fn * 16 + cf)] = (bf16)acc[fm][fn][r];
}

// E[b][i][j] = exp2(qT.kT); rowsum[b][i] += partials (atomic)
__global__ __launch_bounds__(256) void se_gemm_kernel(
    const bf16* __restrict__ qT, const bf16* __restrict__ kT,
    bf16* __restrict__ E, float* __restrict__ rowsum)
{
    const int b = blockIdx.z;
    const size_t CN = (size_t)CC * NN;
    const bf16* qT_b = qT + (size_t)b * CN;
    const bf16* kT_b = kT + (size_t)b * CN;
    bf16* E_b = E + (size_t)b * NN * NN;
    float* rs_b = rowsum + (size_t)b * NN;
    const int m0 = blockIdx.y * BM, n0 = blockIdx.x * BN;
    f32x4 acc[4][4] = {};
    gemm_core(qT_b, CC, kT_b, CC, 0, CC, m0, n0, acc);
    const int lane = threadIdx.x & 63, wid = threadIdx.x >> 6;
    const int wm = (wid >> 1) * 64, wn = (wid & 1) * 64;
    const int cf = lane & 15, rb = (lane >> 4) * 4;
    #pragma unroll
    for (int fm = 0; fm < 4; ++fm)
      #pragma unroll
      for (int fn = 0; fn < 4; ++fn)
        #pragma unroll
        for (int r = 0; r < 4; ++r) {
            float e = exp2f(fminf(acc[fm][fn][r], 86.f));
            acc[fm][fn][r] = e;
            E_b[(size_t)(m0 + wm + fm * 16 + rb + r) * NN
                + (n0 + wn + fn * 16 + cf)] = (bf16)e;
        }
    #pragma unroll
    for (int fm = 0; fm < 4; ++fm)
      #pragma unroll
      for (int r = 0; r < 4; ++r) {
          float s = acc[fm][0][r] + acc[fm][1][r] + acc[fm][2][r] + acc[fm][3][r];
          s += __shfl_xor(s, 1); s += __shfl_xor(s, 2);
          s += __shfl_xor(s, 4); s += __shfl_xor(s, 8);
          if (cf == 0)
              atomicAdd(&rs_b[m0 + wm + fm * 16 + rb + r], s);
      }
}

// out[b][o][n] = (sum_j W~[b][o][j]*E[b][n][j]) / rowsum[b][n]
//               + wb[o] + pb[o] + x[b][o][n]       (M=512,N=4096,K=4096)
__global__ __launch_bounds__(256) void pvproj_kernel(
    const bf16* __restrict__ Wt, const bf16* __restrict__ E,
    const float* __restrict__ rowsum, const float* __restrict__ wb,
    const float* __restrict__ pb, const float* __restrict__ x,
    float* __restrict__ outp)
{
    const int b = blockIdx.z;
    const size_t CN = (size_t)CC * NN;
    const int m0 = blockIdx.y * 64, n0 = blockIdx.x * BN;
    f32x4 acc[2][4] = {};
    gemm_core64(Wt + (size_t)b * CN, NN, E + (size_t)b * NN * NN, NN,
                0, NN, m0, n0, acc);
    const float* rs_b = rowsum + (size_t)b * NN;
    const int lane = threadIdx.x & 63, wid = threadIdx.x >> 6;
    const int wm = (wid >> 1) * 32, wn = (wid & 1) * 64;
    const int cf = lane & 15, rb = (lane >> 4) * 4;
    #pragma unroll
    for (int fm = 0; fm < 2; ++fm)
      #pragma unroll
      for (int fn = 0; fn < 4; ++fn) {
          const int col = n0 + wn + fn * 16 + cf;     // n
          const float inv = 1.f / rs_b[col];
          #pragma unroll
          for (int r = 0; r < 4; ++r) {
              const int row = m0 + wm + fm * 16 + rb + r;   // o
              const size_t idx = (size_t)b * CN + (size_t)row * NN + col;
              outp[idx] = acc[fm][fn][r] * inv + wb[row] + pb[row] + x[idx];
          }
      }
}

// ---------------------------------------------------------------------------
extern "C" void kernel_launch(void* const* d_in, const int* in_sizes, int n_in,
                              void* d_out, int out_size, void* d_ws, size_t ws_size,
                              hipStream_t stream)
{
    const float* x   = (const float*)d_in[0];
    const float* gnw = (const float*)d_in[1];
    const float* gnb = (const float*)d_in[2];
    const float* qw  = (const float*)d_in[3];
    const float* qb  = (const float*)d_in[4];
    const float* kw  = (const float*)d_in[5];
    const float* kb  = (const float*)d_in[6];
    const float* vw  = (const float*)d_in[7];
    const float* vb  = (const float*)d_in[8];
    const float* pw  = (const float*)d_in[9];
    const float* pb  = (const float*)d_in[10];
    float* outp = (float*)d_out;

    char* ws = (char*)d_ws;
    size_t off = 0;
    auto alloc = [&](size_t bytes) -> char* {
        char* p = ws + off;
        off = (off + bytes + 255) & ~(size_t)255;
        return p;
    };
    const size_t CN = (size_t)CC * NN;
    bf16*  wbf  = (bf16*)alloc(4 * (size_t)CC * CC * sizeof(bf16));   // 2MB: q,k,vwT,pw
    bf16*  hT   = (bf16*)alloc(2 * CN * sizeof(bf16));                // 8MB
    bf16*  qT   = (bf16*)alloc(2 * CN * sizeof(bf16));                // 8MB
    bf16*  kT   = (bf16*)alloc(2 * CN * sizeof(bf16));                // 8MB
    bf16*  fw   = (bf16*)alloc((size_t)CC * CC * sizeof(bf16));       // 0.5MB
    bf16*  Wt   = (bf16*)alloc(2 * CN * sizeof(bf16));                // 8MB
    bf16*  E    = (bf16*)alloc(2 * (size_t)NN * NN * sizeof(bf16));   // 64MB
    float* rowsum = (float*)alloc(2 * NN * sizeof(float));            // 32KB
    float* wb   = (float*)alloc(CC * sizeof(float));
    float* mr   = (float*)alloc(64 * 2 * sizeof(float));

    bf16* vwT = wbf + 2 * (size_t)CC * CC;
    bf16* pwb = wbf + 3 * (size_t)CC * CC;

    convert_w_kernel<<<dim3(256, 3), 256, 0, stream>>>(qw, kw, pw, wbf);
    vwT_kernel<<<dim3(8, 8), 256, 0, stream>>>(vw, vwT);
    wb_kernel<<<2, 256, 0, stream>>>(pw, vb, wb);
    gn_stats_kernel<<<64, 256, 0, stream>>>(x, mr);
    gn_apply_T_kernel<<<dim3(NN / 64, CC / 64, 2), 256, 0, stream>>>(
        x, gnw, gnb, mr, hT);
    hipMemsetAsync(rowsum, 0, 2 * NN * sizeof(float), stream);

    fw_gemm_kernel<<<dim3(4, 4), 256, 0, stream>>>(pwb, vwT, fw);
    qk_gemm_kernel<<<dim3(CC / BN, NN / BM, 4), 256, 0, stream>>>(
        hT, wbf, qb, kb, qT, kT);
    w_gemm_kernel<<<dim3(NN / BN, 8, 2), 256, 0, stream>>>(fw, hT, Wt);

    se_gemm_kernel<<<dim3(NN / BN, NN / BM, 2), 256, 0, stream>>>(
        qT, kT, E, rowsum);

    pvproj_kernel<<<dim3(NN / BN, 8, 2), 256, 0, stream>>>(
        Wt, E, rowsum, wb, pb, x, outp);
}